// Round 1
// baseline (2208.603 us; speedup 1.0000x reference)
//
#include <hip/hip_runtime.h>

typedef unsigned short u16;
typedef unsigned int u32;
typedef __attribute__((ext_vector_type(8))) short short8;
typedef __attribute__((ext_vector_type(4))) float f32x4;

#define LDSS 56  // padded LDS row stride (elements); 112B rows keep 16B alignment, ~2-way banks

// ---------- bf16 helpers (manual, RNE) ----------
__device__ inline u16 f2b(float f) {
  u32 u = __builtin_bit_cast(u32, f);
  u += 0x7fff + ((u >> 16) & 1);
  return (u16)(u >> 16);
}
__device__ inline float b2f(u16 u) {
  return __builtin_bit_cast(float, (u32)u << 16);
}

// ---------- 8-element row loaders -> packed bf16 (uint4) ----------
template <typename T> struct Ld8;
template <> struct Ld8<float> {
  static __device__ inline uint4 ld(const float* p) {
    const float4 v0 = *reinterpret_cast<const float4*>(p);
    const float4 v1 = *reinterpret_cast<const float4*>(p + 4);
    uint4 r;
    r.x = (u32)f2b(v0.x) | ((u32)f2b(v0.y) << 16);
    r.y = (u32)f2b(v0.z) | ((u32)f2b(v0.w) << 16);
    r.z = (u32)f2b(v1.x) | ((u32)f2b(v1.y) << 16);
    r.w = (u32)f2b(v1.z) | ((u32)f2b(v1.w) << 16);
    return r;
  }
};
template <> struct Ld8<u16> {
  static __device__ inline uint4 ld(const u16* p) {
    return *reinterpret_cast<const uint4*>(p);
  }
};

template <typename T> __device__ inline void ld8_arr(const T* p, u16* out);
template <> __device__ inline void ld8_arr<float>(const float* p, u16* out) {
  const float4 v0 = *reinterpret_cast<const float4*>(p);
  const float4 v1 = *reinterpret_cast<const float4*>(p + 4);
  out[0] = f2b(v0.x); out[1] = f2b(v0.y); out[2] = f2b(v0.z); out[3] = f2b(v0.w);
  out[4] = f2b(v1.x); out[5] = f2b(v1.y); out[6] = f2b(v1.z); out[7] = f2b(v1.w);
}
template <> __device__ inline void ld8_arr<u16>(const u16* p, u16* out) {
  const uint4 v = *reinterpret_cast<const uint4*>(p);
  out[0] = (u16)(v.x & 0xffff); out[1] = (u16)(v.x >> 16);
  out[2] = (u16)(v.y & 0xffff); out[3] = (u16)(v.y >> 16);
  out[4] = (u16)(v.z & 0xffff); out[5] = (u16)(v.z >> 16);
  out[6] = (u16)(v.w & 0xffff); out[7] = (u16)(v.w >> 16);
}

// ---------- epilogue store helpers ----------
__device__ inline float c_to_f(float v) { return v; }
__device__ inline float c_to_f(u16 v) { return b2f(v); }
__device__ inline void c_store(float* p, float v) { *p = v; }
__device__ inline void c_store(u16* p, float v) { *p = f2b(v); }

// =====================================================================
// GEMM: C[M,N] = alpha * A[M,K] * B + bias[n] + beta * C
//   BT=false: B is [K,N] row-major (NN).  BT=true: B is [N,K] row-major (NT).
//   All of M%64==0, N%64==0, K%32==0 hold for every call in this pipeline.
//   Tile 64x64xBK32; 4 waves in 2x2; each wave 32x32 via 2x2 mfma 16x16x32.
//   MFMA layouts per measured m89/m91/m120:
//     A-frag: A[m=lane&15][k=(lane>>4)*8+j]     (8 contiguous k -> ds_read_b128)
//     B-frag: B[k=(lane>>4)*8+j][n=lane&15]     (Bs stored [n][k] -> contiguous)
//     C/D   : row=(lane>>4)*4+reg, col=lane&15
// =====================================================================
template <typename TA, typename TB, typename TC, bool BT>
__global__ __launch_bounds__(256) void gemm_kernel(
    const TA* A, long lda, long strideA,
    const TB* B, long ldb, long strideB,
    TC* C, long ldc, long strideC,
    int M, int N, int K,
    float alpha, const float* bias, float beta) {
  __shared__ u16 As[64 * LDSS];
  __shared__ u16 Bs[64 * LDSS];

  const int tid = threadIdx.x;
  const int bz = blockIdx.z;
  A += (size_t)bz * strideA;
  B += (size_t)bz * strideB;
  C += (size_t)bz * strideC;
  const int n0 = blockIdx.x * 64;
  const int m0 = blockIdx.y * 64;

  const int lane = tid & 63;
  const int wave = tid >> 6;
  const int wm = (wave >> 1) << 5;  // wave row offset in tile
  const int wn = (wave & 1) << 5;   // wave col offset in tile
  const int rowin = lane & 15;
  const int ko8 = (lane >> 4) << 3;

  f32x4 acc00 = {0.f, 0.f, 0.f, 0.f};
  f32x4 acc01 = {0.f, 0.f, 0.f, 0.f};
  f32x4 acc10 = {0.f, 0.f, 0.f, 0.f};
  f32x4 acc11 = {0.f, 0.f, 0.f, 0.f};

  const int sr = tid >> 2;        // 0..63 staging row
  const int sc = (tid & 3) << 3;  // 0,8,16,24 staging col
  const int bkc = tid & 31;       // NN staging: k within tile
  const int bnn = (tid >> 5) << 3;// NN staging: n group of 8

  for (int kk = 0; kk < K; kk += 32) {
    *reinterpret_cast<uint4*>(&As[sr * LDSS + sc]) =
        Ld8<TA>::ld(A + (size_t)(m0 + sr) * lda + kk + sc);
    if constexpr (BT) {
      *reinterpret_cast<uint4*>(&Bs[sr * LDSS + sc]) =
          Ld8<TB>::ld(B + (size_t)(n0 + sr) * ldb + kk + sc);
    } else {
      u16 tmp[8];
      ld8_arr<TB>(B + (size_t)(kk + bkc) * ldb + n0 + bnn, tmp);
#pragma unroll
      for (int i = 0; i < 8; ++i) Bs[(bnn + i) * LDSS + bkc] = tmp[i];
    }
    __syncthreads();

    const u16* ap = &As[(wm + rowin) * LDSS + ko8];
    const u16* bp = &Bs[(wn + rowin) * LDSS + ko8];
    const short8 a0 = *reinterpret_cast<const short8*>(ap);
    const short8 a1 = *reinterpret_cast<const short8*>(ap + 16 * LDSS);
    const short8 b0 = *reinterpret_cast<const short8*>(bp);
    const short8 b1 = *reinterpret_cast<const short8*>(bp + 16 * LDSS);
    acc00 = __builtin_amdgcn_mfma_f32_16x16x32_bf16(a0, b0, acc00, 0, 0, 0);
    acc01 = __builtin_amdgcn_mfma_f32_16x16x32_bf16(a0, b1, acc01, 0, 0, 0);
    acc10 = __builtin_amdgcn_mfma_f32_16x16x32_bf16(a1, b0, acc10, 0, 0, 0);
    acc11 = __builtin_amdgcn_mfma_f32_16x16x32_bf16(a1, b1, acc11, 0, 0, 0);
    __syncthreads();
  }

  const int colb = n0 + wn + rowin;
  const int rowb = m0 + wm + ((lane >> 4) << 2);
#pragma unroll
  for (int mi = 0; mi < 2; ++mi) {
    const f32x4 ar0 = mi ? acc10 : acc00;
    const f32x4 ar1 = mi ? acc11 : acc01;
#pragma unroll
    for (int r = 0; r < 4; ++r) {
      const int row = rowb + mi * 16 + r;
      {
        const int col = colb;
        float v = alpha * ar0[r];
        if (bias) v += bias[col];
        const size_t idx = (size_t)row * ldc + col;
        if (beta != 0.f) v += beta * c_to_f(C[idx]);
        c_store(&C[idx], v);
      }
      {
        const int col = colb + 16;
        float v = alpha * ar1[r];
        if (bias) v += bias[col];
        const size_t idx = (size_t)row * ldc + col;
        if (beta != 0.f) v += beta * c_to_f(C[idx]);
        c_store(&C[idx], v);
      }
    }
  }
}

// =====================================================================
// RMSNorm over DIM=1536 (+gain), optional plain output and/or RoPE output.
// x is bf16 [rows][1536]; rope pairs are (2i,2i+1) within each 128-dim head,
// cos/sin indexed [row][i], i = pair&63. In-place safe (reads precede barrier).
// =====================================================================
__global__ __launch_bounds__(256) void rmsnorm_rope_kernel(
    const u16* x, const float* g, const float* rc, const float* rs,
    u16* out_plain, u16* out_rope) {
  __shared__ float red[4];
  const int row = blockIdx.x;
  const int tid = threadIdx.x;
  const u32* xr = reinterpret_cast<const u32*>(x + (size_t)row * 1536);
  float xe[3], xo[3];
  float ss = 0.f;
#pragma unroll
  for (int j = 0; j < 3; ++j) {
    const u32 u = xr[tid + 256 * j];
    const float e = b2f((u16)(u & 0xffff));
    const float o = b2f((u16)(u >> 16));
    xe[j] = e; xo[j] = o;
    ss += e * e + o * o;
  }
#pragma unroll
  for (int off = 32; off; off >>= 1) ss += __shfl_xor(ss, off, 64);
  if ((tid & 63) == 0) red[tid >> 6] = ss;
  __syncthreads();
  const float total = red[0] + red[1] + red[2] + red[3];
  const float rinv = rsqrtf(total * (1.0f / 1536.0f) + 1e-6f);
  u32* po = out_plain ? reinterpret_cast<u32*>(out_plain + (size_t)row * 1536) : nullptr;
  u32* pr = out_rope ? reinterpret_cast<u32*>(out_rope + (size_t)row * 1536) : nullptr;
#pragma unroll
  for (int j = 0; j < 3; ++j) {
    const int p = tid + 256 * j;
    const float2 gg = reinterpret_cast<const float2*>(g)[p];
    const float e = xe[j] * rinv * gg.x;
    const float o = xo[j] * rinv * gg.y;
    if (po) po[p] = (u32)f2b(e) | ((u32)f2b(o) << 16);
    if (pr) {
      const int i = p & 63;
      const float c = rc[row * 64 + i];
      const float s = rs[row * 64 + i];
      const float re = e * c - o * s;
      const float im = e * s + o * c;
      pr[p] = (u32)f2b(re) | ((u32)f2b(im) << 16);
    }
  }
}

// =====================================================================
// Exact row softmax, len = NPT*256 f32, in place.
// =====================================================================
template <int NPT>
__global__ __launch_bounds__(256) void softmax_kernel(float* S, int len) {
  __shared__ float red[4];
  float* p = S + (size_t)blockIdx.x * len;
  const int tid = threadIdx.x;
  float v[NPT];
  float m = -3.0e38f;
#pragma unroll
  for (int j = 0; j < NPT; ++j) {
    v[j] = p[tid + 256 * j];
    m = fmaxf(m, v[j]);
  }
#pragma unroll
  for (int off = 32; off; off >>= 1) m = fmaxf(m, __shfl_xor(m, off, 64));
  if ((tid & 63) == 0) red[tid >> 6] = m;
  __syncthreads();
  m = fmaxf(fmaxf(red[0], red[1]), fmaxf(red[2], red[3]));
  __syncthreads();
  float s = 0.f;
#pragma unroll
  for (int j = 0; j < NPT; ++j) {
    v[j] = expf(v[j] - m);
    s += v[j];
  }
#pragma unroll
  for (int off = 32; off; off >>= 1) s += __shfl_xor(s, off, 64);
  if ((tid & 63) == 0) red[tid >> 6] = s;
  __syncthreads();
  s = red[0] + red[1] + red[2] + red[3];
  const float inv = 1.0f / s;
#pragma unroll
  for (int j = 0; j < NPT; ++j) p[tid + 256 * j] = v[j] * inv;
}

// =====================================================================
// Host orchestration
// =====================================================================
extern "C" void kernel_launch(void* const* d_in, const int* in_sizes, int n_in,
                              void* d_out, int out_size, void* d_ws, size_t ws_size,
                              hipStream_t stream) {
  (void)in_sizes; (void)n_in; (void)out_size;
  constexpr int T = 4096, TR = 1024, DIM = 1536, NH = 12;
  const float scale = 0.08838834764831843f;  // 1/sqrt(128)

  const float* hs  = (const float*)d_in[0];
  const float* rhs = (const float*)d_in[1];
  const float* rc  = (const float*)d_in[2];
  const float* rs  = (const float*)d_in[3];
  const float* Wq  = (const float*)d_in[4];
  const float* bq  = (const float*)d_in[5];
  const float* Wk  = (const float*)d_in[6];
  const float* bk  = (const float*)d_in[7];
  const float* Wv  = (const float*)d_in[8];
  const float* bv  = (const float*)d_in[9];
  const float* Wkr = (const float*)d_in[10];
  const float* bkr = (const float*)d_in[11];
  const float* Wvr = (const float*)d_in[12];
  const float* bvr = (const float*)d_in[13];
  const float* Wo  = (const float*)d_in[14];
  const float* bo  = (const float*)d_in[15];
  const float* gq  = (const float*)d_in[16];
  const float* gk  = (const float*)d_in[17];
  float* out = (float*)d_out;

  char* ws = (char*)d_ws;
  size_t off = 0;
  auto alloc = [&](size_t bytes) -> void* {
    void* p = ws + off;
    off += (bytes + 255) & ~(size_t)255;
    return p;
  };
  u16* bQ  = (u16*)alloc((size_t)T * DIM * 2);   // qn (plain, post-rmsnorm)
  u16* bQr = (u16*)alloc((size_t)T * DIM * 2);   // rope(qn)
  u16* bK  = (u16*)alloc((size_t)T * DIM * 2);   // rope(rmsnorm(k_lin))
  u16* bV  = (u16*)alloc((size_t)T * DIM * 2);   // v_lin
  u16* bKr = (u16*)alloc((size_t)TR * DIM * 2);  // ref_k
  u16* bVr = (u16*)alloc((size_t)TR * DIM * 2);  // ref_v
  float* bO = (float*)alloc((size_t)T * DIM * 4);// main+ref attention out (f32)

  // Score-chunk size: prefer 512 (12*512*4096*4 = 100 MB stays L3-resident)
  int QC = 64;
  const int cands[4] = {512, 256, 128, 64};
  for (int i = 0; i < 4; ++i) {
    const size_t sbytes = (size_t)12 * cands[i] * 4096 * 4;
    if (off + sbytes <= ws_size) { QC = cands[i]; break; }
  }
  float* S = (float*)alloc((size_t)12 * QC * 4096 * 4);

  const dim3 blk(256);

  // --- projections (f32 in -> bf16 out, bias) ---
  gemm_kernel<float, float, u16, false><<<dim3(24, 64, 1), blk, 0, stream>>>(
      hs, DIM, 0, Wq, DIM, 0, bQ, DIM, 0, T, DIM, DIM, 1.f, bq, 0.f);
  gemm_kernel<float, float, u16, false><<<dim3(24, 64, 1), blk, 0, stream>>>(
      hs, DIM, 0, Wk, DIM, 0, bK, DIM, 0, T, DIM, DIM, 1.f, bk, 0.f);
  gemm_kernel<float, float, u16, false><<<dim3(24, 64, 1), blk, 0, stream>>>(
      hs, DIM, 0, Wv, DIM, 0, bV, DIM, 0, T, DIM, DIM, 1.f, bv, 0.f);
  gemm_kernel<float, float, u16, false><<<dim3(24, 16, 1), blk, 0, stream>>>(
      rhs, DIM, 0, Wkr, DIM, 0, bKr, DIM, 0, TR, DIM, DIM, 1.f, bkr, 0.f);
  gemm_kernel<float, float, u16, false><<<dim3(24, 16, 1), blk, 0, stream>>>(
      rhs, DIM, 0, Wvr, DIM, 0, bVr, DIM, 0, TR, DIM, DIM, 1.f, bvr, 0.f);

  // --- rmsnorm / rope ---
  rmsnorm_rope_kernel<<<T, blk, 0, stream>>>(bQ, gq, rc, rs, bQ, bQr);      // qn + rope(qn)
  rmsnorm_rope_kernel<<<T, blk, 0, stream>>>(bK, gk, rc, rs, nullptr, bK);  // rope(kn) in place
  rmsnorm_rope_kernel<<<TR, blk, 0, stream>>>(bKr, gk, nullptr, nullptr, bKr, nullptr);

  const int nchunk = T / QC;

  // --- ref (cross) attention: writes bO (beta=0) ---
  for (int c = 0; c < nchunk; ++c) {
    gemm_kernel<u16, u16, float, true><<<dim3(TR / 64, QC / 64, NH), blk, 0, stream>>>(
        bQ + (size_t)c * QC * DIM, DIM, 128, bKr, DIM, 128,
        S, TR, (long)QC * TR, QC, TR, 128, scale, nullptr, 0.f);
    softmax_kernel<4><<<NH * QC, blk, 0, stream>>>(S, TR);
    gemm_kernel<float, u16, float, false><<<dim3(2, QC / 64, NH), blk, 0, stream>>>(
        S, TR, (long)QC * TR, bVr, DIM, 128,
        bO + (size_t)c * QC * DIM, DIM, 128, QC, 128, TR, 1.f, nullptr, 0.f);
  }

  // --- main (self) attention: accumulates into bO (beta=1) ---
  for (int c = 0; c < nchunk; ++c) {
    gemm_kernel<u16, u16, float, true><<<dim3(T / 64, QC / 64, NH), blk, 0, stream>>>(
        bQr + (size_t)c * QC * DIM, DIM, 128, bK, DIM, 128,
        S, T, (long)QC * T, QC, T, 128, scale, nullptr, 0.f);
    softmax_kernel<16><<<NH * QC, blk, 0, stream>>>(S, T);
    gemm_kernel<float, u16, float, false><<<dim3(2, QC / 64, NH), blk, 0, stream>>>(
        S, T, (long)QC * T, bV, DIM, 128,
        bO + (size_t)c * QC * DIM, DIM, 128, QC, 128, T, 1.f, nullptr, 1.f);
  }

  // --- output projection (f32 in/out) ---
  gemm_kernel<float, float, float, false><<<dim3(24, 64, 1), blk, 0, stream>>>(
      bO, DIM, 0, Wo, DIM, 0, out, DIM, 0, T, DIM, DIM, 1.f, bo, 0.f);
}

// Round 2
// 956.631 us; speedup vs baseline: 2.3087x; 2.3087x over previous
//
#include <hip/hip_runtime.h>

typedef unsigned short u16;
typedef unsigned int u32;
typedef __attribute__((ext_vector_type(8))) short short8;
typedef __attribute__((ext_vector_type(4))) float f32x4;

#define LDSS 56  // padded LDS row stride (elements); 112B rows keep 16B alignment, ~2-way banks

// ---------- bf16 helpers (manual, RNE) ----------
__device__ inline u16 f2b(float f) {
  u32 u = __builtin_bit_cast(u32, f);
  u += 0x7fff + ((u >> 16) & 1);
  return (u16)(u >> 16);
}
__device__ inline float b2f(u16 u) {
  return __builtin_bit_cast(float, (u32)u << 16);
}

// ---------- 8-element row loaders -> packed bf16 (uint4) ----------
template <typename T> struct Ld8;
template <> struct Ld8<float> {
  static __device__ inline uint4 ld(const float* p) {
    const float4 v0 = *reinterpret_cast<const float4*>(p);
    const float4 v1 = *reinterpret_cast<const float4*>(p + 4);
    uint4 r;
    r.x = (u32)f2b(v0.x) | ((u32)f2b(v0.y) << 16);
    r.y = (u32)f2b(v0.z) | ((u32)f2b(v0.w) << 16);
    r.z = (u32)f2b(v1.x) | ((u32)f2b(v1.y) << 16);
    r.w = (u32)f2b(v1.z) | ((u32)f2b(v1.w) << 16);
    return r;
  }
};
template <> struct Ld8<u16> {
  static __device__ inline uint4 ld(const u16* p) {
    return *reinterpret_cast<const uint4*>(p);
  }
};

template <typename T> __device__ inline void ld8_arr(const T* p, u16* out);
template <> __device__ inline void ld8_arr<float>(const float* p, u16* out) {
  const float4 v0 = *reinterpret_cast<const float4*>(p);
  const float4 v1 = *reinterpret_cast<const float4*>(p + 4);
  out[0] = f2b(v0.x); out[1] = f2b(v0.y); out[2] = f2b(v0.z); out[3] = f2b(v0.w);
  out[4] = f2b(v1.x); out[5] = f2b(v1.y); out[6] = f2b(v1.z); out[7] = f2b(v1.w);
}
template <> __device__ inline void ld8_arr<u16>(const u16* p, u16* out) {
  const uint4 v = *reinterpret_cast<const uint4*>(p);
  out[0] = (u16)(v.x & 0xffff); out[1] = (u16)(v.x >> 16);
  out[2] = (u16)(v.y & 0xffff); out[3] = (u16)(v.y >> 16);
  out[4] = (u16)(v.z & 0xffff); out[5] = (u16)(v.z >> 16);
  out[6] = (u16)(v.w & 0xffff); out[7] = (u16)(v.w >> 16);
}

// ---------- epilogue store helpers ----------
__device__ inline float c_to_f(float v) { return v; }
__device__ inline float c_to_f(u16 v) { return b2f(v); }
__device__ inline void c_store(float* p, float v) { *p = v; }
__device__ inline void c_store(u16* p, float v) { *p = f2b(v); }

// =====================================================================
// GEMM (unchanged from Round 1, verified passing): C = alpha*A*B + bias + beta*C
// =====================================================================
template <typename TA, typename TB, typename TC, bool BT>
__global__ __launch_bounds__(256) void gemm_kernel(
    const TA* A, long lda, long strideA,
    const TB* B, long ldb, long strideB,
    TC* C, long ldc, long strideC,
    int M, int N, int K,
    float alpha, const float* bias, float beta) {
  __shared__ u16 As[64 * LDSS];
  __shared__ u16 Bs[64 * LDSS];

  const int tid = threadIdx.x;
  const int bz = blockIdx.z;
  A += (size_t)bz * strideA;
  B += (size_t)bz * strideB;
  C += (size_t)bz * strideC;
  const int n0 = blockIdx.x * 64;
  const int m0 = blockIdx.y * 64;

  const int lane = tid & 63;
  const int wave = tid >> 6;
  const int wm = (wave >> 1) << 5;
  const int wn = (wave & 1) << 5;
  const int rowin = lane & 15;
  const int ko8 = (lane >> 4) << 3;

  f32x4 acc00 = {0.f, 0.f, 0.f, 0.f};
  f32x4 acc01 = {0.f, 0.f, 0.f, 0.f};
  f32x4 acc10 = {0.f, 0.f, 0.f, 0.f};
  f32x4 acc11 = {0.f, 0.f, 0.f, 0.f};

  const int sr = tid >> 2;
  const int sc = (tid & 3) << 3;
  const int bkc = tid & 31;
  const int bnn = (tid >> 5) << 3;

  for (int kk = 0; kk < K; kk += 32) {
    *reinterpret_cast<uint4*>(&As[sr * LDSS + sc]) =
        Ld8<TA>::ld(A + (size_t)(m0 + sr) * lda + kk + sc);
    if constexpr (BT) {
      *reinterpret_cast<uint4*>(&Bs[sr * LDSS + sc]) =
          Ld8<TB>::ld(B + (size_t)(n0 + sr) * ldb + kk + sc);
    } else {
      u16 tmp[8];
      ld8_arr<TB>(B + (size_t)(kk + bkc) * ldb + n0 + bnn, tmp);
#pragma unroll
      for (int i = 0; i < 8; ++i) Bs[(bnn + i) * LDSS + bkc] = tmp[i];
    }
    __syncthreads();

    const u16* ap = &As[(wm + rowin) * LDSS + ko8];
    const u16* bp = &Bs[(wn + rowin) * LDSS + ko8];
    const short8 a0 = *reinterpret_cast<const short8*>(ap);
    const short8 a1 = *reinterpret_cast<const short8*>(ap + 16 * LDSS);
    const short8 b0 = *reinterpret_cast<const short8*>(bp);
    const short8 b1 = *reinterpret_cast<const short8*>(bp + 16 * LDSS);
    acc00 = __builtin_amdgcn_mfma_f32_16x16x32_bf16(a0, b0, acc00, 0, 0, 0);
    acc01 = __builtin_amdgcn_mfma_f32_16x16x32_bf16(a0, b1, acc01, 0, 0, 0);
    acc10 = __builtin_amdgcn_mfma_f32_16x16x32_bf16(a1, b0, acc10, 0, 0, 0);
    acc11 = __builtin_amdgcn_mfma_f32_16x16x32_bf16(a1, b1, acc11, 0, 0, 0);
    __syncthreads();
  }

  const int colb = n0 + wn + rowin;
  const int rowb = m0 + wm + ((lane >> 4) << 2);
#pragma unroll
  for (int mi = 0; mi < 2; ++mi) {
    const f32x4 ar0 = mi ? acc10 : acc00;
    const f32x4 ar1 = mi ? acc11 : acc01;
#pragma unroll
    for (int r = 0; r < 4; ++r) {
      const int row = rowb + mi * 16 + r;
      {
        const int col = colb;
        float v = alpha * ar0[r];
        if (bias) v += bias[col];
        const size_t idx = (size_t)row * ldc + col;
        if (beta != 0.f) v += beta * c_to_f(C[idx]);
        c_store(&C[idx], v);
      }
      {
        const int col = colb + 16;
        float v = alpha * ar1[r];
        if (bias) v += bias[col];
        const size_t idx = (size_t)row * ldc + col;
        if (beta != 0.f) v += beta * c_to_f(C[idx]);
        c_store(&C[idx], v);
      }
    }
  }
}

// =====================================================================
// RMSNorm (+gain), optional plain and/or RoPE output (unchanged, verified)
// =====================================================================
__global__ __launch_bounds__(256) void rmsnorm_rope_kernel(
    const u16* x, const float* g, const float* rc, const float* rs,
    u16* out_plain, u16* out_rope) {
  __shared__ float red[4];
  const int row = blockIdx.x;
  const int tid = threadIdx.x;
  const u32* xr = reinterpret_cast<const u32*>(x + (size_t)row * 1536);
  float xe[3], xo[3];
  float ss = 0.f;
#pragma unroll
  for (int j = 0; j < 3; ++j) {
    const u32 u = xr[tid + 256 * j];
    const float e = b2f((u16)(u & 0xffff));
    const float o = b2f((u16)(u >> 16));
    xe[j] = e; xo[j] = o;
    ss += e * e + o * o;
  }
#pragma unroll
  for (int off = 32; off; off >>= 1) ss += __shfl_xor(ss, off, 64);
  if ((tid & 63) == 0) red[tid >> 6] = ss;
  __syncthreads();
  const float total = red[0] + red[1] + red[2] + red[3];
  const float rinv = rsqrtf(total * (1.0f / 1536.0f) + 1e-6f);
  u32* po = out_plain ? reinterpret_cast<u32*>(out_plain + (size_t)row * 1536) : nullptr;
  u32* pr = out_rope ? reinterpret_cast<u32*>(out_rope + (size_t)row * 1536) : nullptr;
#pragma unroll
  for (int j = 0; j < 3; ++j) {
    const int p = tid + 256 * j;
    const float2 gg = reinterpret_cast<const float2*>(g)[p];
    const float e = xe[j] * rinv * gg.x;
    const float o = xo[j] * rinv * gg.y;
    if (po) po[p] = (u32)f2b(e) | ((u32)f2b(o) << 16);
    if (pr) {
      const int i = p & 63;
      const float c = rc[row * 64 + i];
      const float s = rs[row * 64 + i];
      const float re = e * c - o * s;
      const float im = e * s + o * c;
      pr[p] = (u32)f2b(re) | ((u32)f2b(im) << 16);
    }
  }
}

// =====================================================================
// Per-head V transpose: V bf16 [kvLen][1536] -> Vt bf16 [NH][128][kvLen]
// grid (kvLen/64, 12), 256 threads. LDS-tiled, coalesced both sides.
// =====================================================================
__global__ __launch_bounds__(256) void vtrans_kernel(
    const u16* __restrict__ V, u16* __restrict__ Vt, int kvLen) {
  __shared__ u16 Ls[64 * 136];
  const int tid = threadIdx.x;
  const int h = blockIdx.y;
  const int kv0 = blockIdx.x * 64;
#pragma unroll
  for (int i = 0; i < 4; ++i) {
    const int c = tid + 256 * i;
    const int row = c >> 4, c8 = c & 15;
    *reinterpret_cast<uint4*>(&Ls[row * 136 + 8 * c8]) =
        *reinterpret_cast<const uint4*>(V + (size_t)(kv0 + row) * 1536 + h * 128 + 8 * c8);
  }
  __syncthreads();
#pragma unroll
  for (int i = 0; i < 4; ++i) {
    const int c = tid + 256 * i;
    const int d = c >> 3, kc = c & 7;
    u16 tmp[8];
#pragma unroll
    for (int j = 0; j < 8; ++j) tmp[j] = Ls[(8 * kc + j) * 136 + d];
    *reinterpret_cast<uint4*>(Vt + ((size_t)h * 128 + d) * kvLen + kv0 + 8 * kc) =
        *reinterpret_cast<const uint4*>(tmp);
  }
}

// =====================================================================
// Fused flash attention, DH=128, BQ=64 (4 waves x 16 q-rows), BKV=64.
//   Q  bf16 [T][1536] (head h at cols h*128..h*128+127)
//   K  bf16 [kvLen][1536]
//   Vt bf16 [NH][128][kvLen]  (pre-transposed)
//   O  f32  [T][1536]; addO: accumulate onto existing contents.
// Computes S^T = K*Q^T per wave so softmax state sits at q = lane&15:
//   St[mt] C-layout: row kpos=16mt+4quad+rr, col q=r -> 16 S-values/lane, one q-row.
// P -> A-frag via wave-private LDS (b64 writes, b128 reads; same-wave DS is in-order).
// Vt LDS tile is chunk-XOR swizzled (c ^= d&7) for conflict-floor b128 reads.
// =====================================================================
#define KSTR 136
#define FSCALE 0.08838834764831843f

__global__ __launch_bounds__(256) void flash_kernel(
    const u16* __restrict__ Q, const u16* __restrict__ K,
    const u16* __restrict__ Vt, float* __restrict__ O,
    int kvLen, int addO) {
  __shared__ u16 Ks[64 * KSTR];     // [kv][d] padded
  __shared__ u16 Vs[128 * 64];      // [d][kv] chunk-swizzled
  __shared__ u16 Pb[4][16 * 72];    // per-wave P: [q][kpos] padded
  __shared__ float ab[4][16];       // per-wave alpha / 1/l broadcast

  const int tid = threadIdx.x;
  const int lane = tid & 63;
  const int w = tid >> 6;
  const int r = lane & 15;
  const int quad = lane >> 4;
  const int h = blockIdx.y;
  const int q0 = blockIdx.x * 64;
  const int qrow = q0 + 16 * w + r;

  // Q fragments (B-operand of S^T): lane holds Q[qrow][32ks+8quad+j]
  short8 qf[4];
  const u16* qbase = Q + (size_t)qrow * 1536 + h * 128 + 8 * quad;
#pragma unroll
  for (int ks = 0; ks < 4; ++ks)
    qf[ks] = *reinterpret_cast<const short8*>(qbase + 32 * ks);

  f32x4 Oc[8];
#pragma unroll
  for (int dt = 0; dt < 8; ++dt) Oc[dt] = (f32x4){0.f, 0.f, 0.f, 0.f};
  float m_i = -1e30f, l_i = 0.f;

  const u16* Vth = Vt + (size_t)h * 128 * kvLen;

  for (int k0 = 0; k0 < kvLen; k0 += 64) {
    __syncthreads();
    // stage K tile [64][128] (padded rows)
#pragma unroll
    for (int i = 0; i < 4; ++i) {
      const int c = tid + 256 * i;
      const int row = c >> 4, c8 = c & 15;
      *reinterpret_cast<uint4*>(&Ks[row * KSTR + 8 * c8]) =
          *reinterpret_cast<const uint4*>(K + (size_t)(k0 + row) * 1536 + h * 128 + 8 * c8);
    }
    // stage Vt tile [128][64], chunk-swizzled
#pragma unroll
    for (int i = 0; i < 4; ++i) {
      const int c = tid + 256 * i;
      const int d = c >> 3, kc = c & 7;
      const int kcs = kc ^ (d & 7);
      *reinterpret_cast<uint4*>(&Vs[d * 64 + 8 * kcs]) =
          *reinterpret_cast<const uint4*>(Vth + (size_t)d * kvLen + k0 + 8 * kc);
    }
    __syncthreads();

    // S^T = K * Q^T : 4 m-tiles (kpos), k=d=128 in 4 steps
    f32x4 St[4];
#pragma unroll
    for (int mt = 0; mt < 4; ++mt) St[mt] = (f32x4){0.f, 0.f, 0.f, 0.f};
#pragma unroll
    for (int mt = 0; mt < 4; ++mt) {
      const u16* kp = &Ks[(16 * mt + r) * KSTR + 8 * quad];
#pragma unroll
      for (int ks = 0; ks < 4; ++ks) {
        const short8 af = *reinterpret_cast<const short8*>(kp + 32 * ks);
        St[mt] = __builtin_amdgcn_mfma_f32_16x16x32_bf16(af, qf[ks], St[mt], 0, 0, 0);
      }
    }

    // online softmax; lane owns q-row (q0+16w+r), 16 kpos values
    float sv[4][4];
    float mloc = -1e30f;
#pragma unroll
    for (int mt = 0; mt < 4; ++mt)
#pragma unroll
      for (int rr = 0; rr < 4; ++rr) {
        const float x = St[mt][rr] * FSCALE;
        sv[mt][rr] = x;
        mloc = fmaxf(mloc, x);
      }
    mloc = fmaxf(mloc, __shfl_xor(mloc, 16, 64));
    mloc = fmaxf(mloc, __shfl_xor(mloc, 32, 64));
    const float mn = fmaxf(m_i, mloc);
    const float alpha = __expf(m_i - mn);
    float psum = 0.f;
    uint2 pk[4];
#pragma unroll
    for (int mt = 0; mt < 4; ++mt) {
      const float p0 = __expf(sv[mt][0] - mn);
      const float p1 = __expf(sv[mt][1] - mn);
      const float p2 = __expf(sv[mt][2] - mn);
      const float p3 = __expf(sv[mt][3] - mn);
      psum += (p0 + p1) + (p2 + p3);
      pk[mt].x = (u32)f2b(p0) | ((u32)f2b(p1) << 16);
      pk[mt].y = (u32)f2b(p2) | ((u32)f2b(p3) << 16);
    }
    psum += __shfl_xor(psum, 16, 64);
    psum += __shfl_xor(psum, 32, 64);
    l_i = l_i * alpha + psum;
    m_i = mn;

    // broadcast alpha from softmax-domain (q=r) to O-domain (q=4quad+rr)
    if (quad == 0) ab[w][r] = alpha;
    // P -> LDS (A-operand layout): row q=r, cols kpos
#pragma unroll
    for (int mt = 0; mt < 4; ++mt)
      *reinterpret_cast<uint2*>(&Pb[w][r * 72 + 16 * mt + 4 * quad]) = pk[mt];

    const float4 a4 = *reinterpret_cast<const float4*>(&ab[w][4 * quad]);
#pragma unroll
    for (int dt = 0; dt < 8; ++dt) {
      Oc[dt][0] *= a4.x; Oc[dt][1] *= a4.y; Oc[dt][2] *= a4.z; Oc[dt][3] *= a4.w;
    }

    const short8 pa0 = *reinterpret_cast<const short8*>(&Pb[w][r * 72 + 8 * quad]);
    const short8 pa1 = *reinterpret_cast<const short8*>(&Pb[w][r * 72 + 32 + 8 * quad]);

    // O += P * V : 8 d-tiles, k=kpos=64 in 2 steps
    const int sw = r & 7;
#pragma unroll
    for (int dt = 0; dt < 8; ++dt) {
      const int d = 16 * dt + r;
      const short8 b0 = *reinterpret_cast<const short8*>(&Vs[d * 64 + 8 * (quad ^ sw)]);
      const short8 b1 = *reinterpret_cast<const short8*>(&Vs[d * 64 + 8 * ((4 + quad) ^ sw)]);
      Oc[dt] = __builtin_amdgcn_mfma_f32_16x16x32_bf16(pa0, b0, Oc[dt], 0, 0, 0);
      Oc[dt] = __builtin_amdgcn_mfma_f32_16x16x32_bf16(pa1, b1, Oc[dt], 0, 0, 0);
    }
  }

  // normalize by 1/l (broadcast via LDS like alpha) and store
  if (quad == 0) ab[w][r] = 1.0f / l_i;
  const float4 li4 = *reinterpret_cast<const float4*>(&ab[w][4 * quad]);
  const float lv[4] = {li4.x, li4.y, li4.z, li4.w};
  float* ob = O + (size_t)(q0 + 16 * w) * 1536 + h * 128;
#pragma unroll
  for (int rr = 0; rr < 4; ++rr) {
    float* orow = ob + (size_t)(4 * quad + rr) * 1536 + r;
#pragma unroll
    for (int dt = 0; dt < 8; ++dt) {
      float v = Oc[dt][rr] * lv[rr];
      if (addO) v += orow[16 * dt];
      orow[16 * dt] = v;
    }
  }
}

// =====================================================================
// Host orchestration
// =====================================================================
extern "C" void kernel_launch(void* const* d_in, const int* in_sizes, int n_in,
                              void* d_out, int out_size, void* d_ws, size_t ws_size,
                              hipStream_t stream) {
  (void)in_sizes; (void)n_in; (void)out_size; (void)ws_size;
  constexpr int T = 4096, TR = 1024, DIM = 1536, NH = 12;

  const float* hs  = (const float*)d_in[0];
  const float* rhs = (const float*)d_in[1];
  const float* rc  = (const float*)d_in[2];
  const float* rs  = (const float*)d_in[3];
  const float* Wq  = (const float*)d_in[4];
  const float* bq  = (const float*)d_in[5];
  const float* Wk  = (const float*)d_in[6];
  const float* bk  = (const float*)d_in[7];
  const float* Wv  = (const float*)d_in[8];
  const float* bv  = (const float*)d_in[9];
  const float* Wkr = (const float*)d_in[10];
  const float* bkr = (const float*)d_in[11];
  const float* Wvr = (const float*)d_in[12];
  const float* bvr = (const float*)d_in[13];
  const float* Wo  = (const float*)d_in[14];
  const float* bo  = (const float*)d_in[15];
  const float* gq  = (const float*)d_in[16];
  const float* gk  = (const float*)d_in[17];
  float* out = (float*)d_out;

  char* ws = (char*)d_ws;
  size_t off = 0;
  auto alloc = [&](size_t bytes) -> void* {
    void* p = ws + off;
    off += (bytes + 255) & ~(size_t)255;
    return p;
  };
  u16* bQ  = (u16*)alloc((size_t)T * DIM * 2);    // rmsnorm(q_lin) (plain)
  u16* bQr = (u16*)alloc((size_t)T * DIM * 2);    // rope(rmsnorm(q_lin))
  u16* bK  = (u16*)alloc((size_t)T * DIM * 2);    // rope(rmsnorm(k_lin))
  u16* bV  = (u16*)alloc((size_t)T * DIM * 2);    // v_lin
  u16* bKr = (u16*)alloc((size_t)TR * DIM * 2);   // ref_k (normed)
  u16* bVr = (u16*)alloc((size_t)TR * DIM * 2);   // ref_v
  float* bO = (float*)alloc((size_t)T * DIM * 4); // attention out (f32)
  u16* VtG = (u16*)alloc((size_t)NH * 128 * T * 2);   // V^T per head
  u16* VtR = (u16*)alloc((size_t)NH * 128 * TR * 2);  // ref V^T per head

  const dim3 blk(256);

  // --- projections (f32 in -> bf16 out, bias) ---
  gemm_kernel<float, float, u16, false><<<dim3(24, 64, 1), blk, 0, stream>>>(
      hs, DIM, 0, Wq, DIM, 0, bQ, DIM, 0, T, DIM, DIM, 1.f, bq, 0.f);
  gemm_kernel<float, float, u16, false><<<dim3(24, 64, 1), blk, 0, stream>>>(
      hs, DIM, 0, Wk, DIM, 0, bK, DIM, 0, T, DIM, DIM, 1.f, bk, 0.f);
  gemm_kernel<float, float, u16, false><<<dim3(24, 64, 1), blk, 0, stream>>>(
      hs, DIM, 0, Wv, DIM, 0, bV, DIM, 0, T, DIM, DIM, 1.f, bv, 0.f);
  gemm_kernel<float, float, u16, false><<<dim3(24, 16, 1), blk, 0, stream>>>(
      rhs, DIM, 0, Wkr, DIM, 0, bKr, DIM, 0, TR, DIM, DIM, 1.f, bkr, 0.f);
  gemm_kernel<float, float, u16, false><<<dim3(24, 16, 1), blk, 0, stream>>>(
      rhs, DIM, 0, Wvr, DIM, 0, bVr, DIM, 0, TR, DIM, DIM, 1.f, bvr, 0.f);

  // --- rmsnorm / rope ---
  rmsnorm_rope_kernel<<<T, blk, 0, stream>>>(bQ, gq, rc, rs, bQ, bQr);
  rmsnorm_rope_kernel<<<T, blk, 0, stream>>>(bK, gk, rc, rs, nullptr, bK);
  rmsnorm_rope_kernel<<<TR, blk, 0, stream>>>(bKr, gk, nullptr, nullptr, bKr, nullptr);

  // --- per-head V transposes ---
  vtrans_kernel<<<dim3(T / 64, NH), blk, 0, stream>>>(bV, VtG, T);
  vtrans_kernel<<<dim3(TR / 64, NH), blk, 0, stream>>>(bVr, VtR, TR);

  // --- fused flash attention: cross (ref) writes, self (main) accumulates ---
  flash_kernel<<<dim3(T / 64, NH), blk, 0, stream>>>(bQ, bKr, VtR, bO, TR, 0);
  flash_kernel<<<dim3(T / 64, NH), blk, 0, stream>>>(bQr, bK, VtG, bO, T, 1);

  // --- output projection (f32 in/out) ---
  gemm_kernel<float, float, float, false><<<dim3(24, 64, 1), blk, 0, stream>>>(
      bO, DIM, 0, Wo, DIM, 0, out, DIM, 0, T, DIM, DIM, 1.f, bo, 0.f);
}

// Round 3
// 609.877 us; speedup vs baseline: 3.6214x; 1.5686x over previous
//
#include <hip/hip_runtime.h>

typedef unsigned short u16;
typedef unsigned int u32;
typedef __attribute__((ext_vector_type(8))) short short8;
typedef __attribute__((ext_vector_type(4))) float f32x4;

// ---------- bf16 helpers (manual, RNE) ----------
__device__ inline u16 f2b(float f) {
  u32 u = __builtin_bit_cast(u32, f);
  u += 0x7fff + ((u >> 16) & 1);
  return (u16)(u >> 16);
}
__device__ inline float b2f(u16 u) {
  return __builtin_bit_cast(float, (u32)u << 16);
}

__device__ inline void c_store(float* p, float v) { *p = v; }
__device__ inline void c_store(u16* p, float v) { *p = f2b(v); }

// ---------- async global->LDS, 16B per lane ----------
// HW contract (m104/m108): LDS dest = wave-uniform base + lane*16; g is per-lane.
typedef const __attribute__((address_space(1))) u32 gu32;
typedef __attribute__((address_space(3))) u32 lu32;
__device__ inline void async16(const u16* g, u16* l) {
  __builtin_amdgcn_global_load_lds((gu32*)g, (lu32*)l, 16, 0, 0);
}

// =====================================================================
// 128x128x(K,BK=32) bf16 GEMM, m97 structure: global_load_lds width-16
// staging, 4 waves 2x2, 4x4 mfma_16x16x32 per wave, 64 f32 acc/lane.
//   A  bf16 [M][K]  (lda=K), M%128==0
//   Bt bf16 [Ntot][K] (ldb=K), Ntot%128==0; output column n = row of Bt.
//   Segmented N: segment s = n/1536 -> C{s} [M][1536] + bias{s}.
// K-chunk XOR swizzle is folded into the staging *global* read order so the
// LDS image is swizzled while global_load_lds keeps its fixed lane order:
//   LDS row r, chunk position p holds global k-chunk p^(r&3).
// Frag mappings as verified in rounds 1-2:
//   A-frag m=lane&15, k=quad*8+j ; B-frag n=lane&15, k=quad*8+j ;
//   C/D row=quad*4+reg, col=lane&15.
// =====================================================================
template <typename TC>
__global__ __launch_bounds__(256) void gemm128_kernel(
    const u16* __restrict__ A, long lda,
    const u16* __restrict__ Bt, long ldb,
    TC* __restrict__ C0, TC* __restrict__ C1, TC* __restrict__ C2, long ldc,
    const float* b0, const float* b1, const float* b2,
    int K) {
  __shared__ u16 As[128 * 32];
  __shared__ u16 Bs[128 * 32];

  const int tid = threadIdx.x;
  const int lane = tid & 63;
  const int w = tid >> 6;
  const int r = lane & 15;
  const int quad = lane >> 4;
  const int m0 = blockIdx.y * 128;
  const int nb = blockIdx.x * 128;
  const int seg = nb / 1536;
  const int nc = nb - seg * 1536;
  TC* C = seg == 0 ? C0 : (seg == 1 ? C1 : C2);
  const float* bias = seg == 0 ? b0 : (seg == 1 ? b1 : b2);

  // staging: wave w covers rows [w*32, w*32+32); lane -> (row = lane>>2,
  // swizzled k-chunk). Same lane key for row and row+16 (16 = 0 mod 4).
  const int srow = lane >> 2;
  const int sx = ((lane & 3) ^ (srow & 3)) * 8;  // swizzled k-chunk, elements
  const u16* Ag = A + (size_t)(m0 + w * 32 + srow) * lda + sx;
  const u16* Bg = Bt + (size_t)(nb + w * 32 + srow) * ldb + sx;
  u16* const Al0 = &As[(w * 32) * 32];
  u16* const Al1 = &As[(w * 32 + 16) * 32];
  u16* const Bl0 = &Bs[(w * 32) * 32];
  u16* const Bl1 = &Bs[(w * 32 + 16) * 32];

  const int wm = (w >> 1) * 64;
  const int wn = (w & 1) * 64;

  f32x4 acc[4][4];
#pragma unroll
  for (int i = 0; i < 4; ++i)
#pragma unroll
    for (int j = 0; j < 4; ++j) acc[i][j] = (f32x4){0.f, 0.f, 0.f, 0.f};

  const int fco = (quad ^ (r & 3)) * 8;  // swizzled frag chunk offset

  for (int kk = 0; kk < K; kk += 32) {
    __syncthreads();
    async16(Ag + kk, Al0);
    async16(Ag + kk + 16 * lda, Al1);
    async16(Bg + kk, Bl0);
    async16(Bg + kk + 16 * ldb, Bl1);
    __syncthreads();

    short8 af[4], bf[4];
#pragma unroll
    for (int mi = 0; mi < 4; ++mi)
      af[mi] = *reinterpret_cast<const short8*>(&As[(wm + 16 * mi + r) * 32 + fco]);
#pragma unroll
    for (int ni = 0; ni < 4; ++ni)
      bf[ni] = *reinterpret_cast<const short8*>(&Bs[(wn + 16 * ni + r) * 32 + fco]);
#pragma unroll
    for (int mi = 0; mi < 4; ++mi)
#pragma unroll
      for (int ni = 0; ni < 4; ++ni)
        acc[mi][ni] = __builtin_amdgcn_mfma_f32_16x16x32_bf16(af[mi], bf[ni], acc[mi][ni], 0, 0, 0);
  }

#pragma unroll
  for (int mi = 0; mi < 4; ++mi)
#pragma unroll
    for (int ni = 0; ni < 4; ++ni)
#pragma unroll
      for (int rr = 0; rr < 4; ++rr) {
        const int row = m0 + wm + 16 * mi + 4 * quad + rr;
        const int col = nc + wn + 16 * ni + r;
        c_store(&C[(size_t)row * ldc + col], acc[mi][ni][rr] + bias[col]);
      }
}

// =====================================================================
// f32 -> bf16 elementwise (8 elems/thread)
// =====================================================================
__global__ __launch_bounds__(256) void conv_kernel(
    const float* __restrict__ x, u16* __restrict__ y, int n8) {
  const int i = blockIdx.x * 256 + threadIdx.x;
  if (i >= n8) return;
  const float4 v0 = reinterpret_cast<const float4*>(x)[2 * i];
  const float4 v1 = reinterpret_cast<const float4*>(x)[2 * i + 1];
  uint4 rv;
  rv.x = (u32)f2b(v0.x) | ((u32)f2b(v0.y) << 16);
  rv.y = (u32)f2b(v0.z) | ((u32)f2b(v0.w) << 16);
  rv.z = (u32)f2b(v1.x) | ((u32)f2b(v1.y) << 16);
  rv.w = (u32)f2b(v1.z) | ((u32)f2b(v1.w) << 16);
  reinterpret_cast<uint4*>(y)[i] = rv;
}

// =====================================================================
// Transpose-convert: W f32 [rows][cols] -> Wt bf16 [cols][rows]
// grid (cols/64, rows/64), 256 threads, 64x64 LDS tile.
// =====================================================================
__global__ __launch_bounds__(256) void transconv_kernel(
    const float* __restrict__ W, u16* __restrict__ Wt, int rows, int cols) {
  __shared__ u16 Ls[64 * 72];
  const int tid = threadIdx.x;
  const int k0 = blockIdx.y * 64;
  const int n0 = blockIdx.x * 64;
#pragma unroll
  for (int i = 0; i < 4; ++i) {
    const int c = tid + 256 * i;      // 0..1023
    const int row = c >> 4;           // 0..63
    const int c4 = (c & 15) * 4;
    const float4 v = *reinterpret_cast<const float4*>(&W[(size_t)(k0 + row) * cols + n0 + c4]);
    Ls[(c4 + 0) * 72 + row] = f2b(v.x);
    Ls[(c4 + 1) * 72 + row] = f2b(v.y);
    Ls[(c4 + 2) * 72 + row] = f2b(v.z);
    Ls[(c4 + 3) * 72 + row] = f2b(v.w);
  }
  __syncthreads();
#pragma unroll
  for (int i = 0; i < 2; ++i) {
    const int c = tid + 256 * i;      // 0..511
    const int n = c >> 3;             // 0..63
    const int kc = (c & 7) * 8;
    u16 tmp[8];
#pragma unroll
    for (int j = 0; j < 8; ++j) tmp[j] = Ls[n * 72 + kc + j];
    *reinterpret_cast<uint4*>(&Wt[(size_t)(n0 + n) * rows + k0 + kc]) =
        *reinterpret_cast<const uint4*>(tmp);
  }
}

// =====================================================================
// RMSNorm (+gain), optional plain and/or RoPE output (verified, unchanged)
// =====================================================================
__global__ __launch_bounds__(256) void rmsnorm_rope_kernel(
    const u16* x, const float* g, const float* rc, const float* rs,
    u16* out_plain, u16* out_rope) {
  __shared__ float red[4];
  const int row = blockIdx.x;
  const int tid = threadIdx.x;
  const u32* xr = reinterpret_cast<const u32*>(x + (size_t)row * 1536);
  float xe[3], xo[3];
  float ss = 0.f;
#pragma unroll
  for (int j = 0; j < 3; ++j) {
    const u32 u = xr[tid + 256 * j];
    const float e = b2f((u16)(u & 0xffff));
    const float o = b2f((u16)(u >> 16));
    xe[j] = e; xo[j] = o;
    ss += e * e + o * o;
  }
#pragma unroll
  for (int off = 32; off; off >>= 1) ss += __shfl_xor(ss, off, 64);
  if ((tid & 63) == 0) red[tid >> 6] = ss;
  __syncthreads();
  const float total = red[0] + red[1] + red[2] + red[3];
  const float rinv = rsqrtf(total * (1.0f / 1536.0f) + 1e-6f);
  u32* po = out_plain ? reinterpret_cast<u32*>(out_plain + (size_t)row * 1536) : nullptr;
  u32* pr = out_rope ? reinterpret_cast<u32*>(out_rope + (size_t)row * 1536) : nullptr;
#pragma unroll
  for (int j = 0; j < 3; ++j) {
    const int p = tid + 256 * j;
    const float2 gg = reinterpret_cast<const float2*>(g)[p];
    const float e = xe[j] * rinv * gg.x;
    const float o = xo[j] * rinv * gg.y;
    if (po) po[p] = (u32)f2b(e) | ((u32)f2b(o) << 16);
    if (pr) {
      const int i = p & 63;
      const float c = rc[row * 64 + i];
      const float s = rs[row * 64 + i];
      const float re = e * c - o * s;
      const float im = e * s + o * c;
      pr[p] = (u32)f2b(re) | ((u32)f2b(im) << 16);
    }
  }
}

// =====================================================================
// Per-head V transpose (verified, unchanged)
// =====================================================================
__global__ __launch_bounds__(256) void vtrans_kernel(
    const u16* __restrict__ V, u16* __restrict__ Vt, int kvLen) {
  __shared__ u16 Ls[64 * 136];
  const int tid = threadIdx.x;
  const int h = blockIdx.y;
  const int kv0 = blockIdx.x * 64;
#pragma unroll
  for (int i = 0; i < 4; ++i) {
    const int c = tid + 256 * i;
    const int row = c >> 4, c8 = c & 15;
    *reinterpret_cast<uint4*>(&Ls[row * 136 + 8 * c8]) =
        *reinterpret_cast<const uint4*>(V + (size_t)(kv0 + row) * 1536 + h * 128 + 8 * c8);
  }
  __syncthreads();
#pragma unroll
  for (int i = 0; i < 4; ++i) {
    const int c = tid + 256 * i;
    const int d = c >> 3, kc = c & 7;
    u16 tmp[8];
#pragma unroll
    for (int j = 0; j < 8; ++j) tmp[j] = Ls[(8 * kc + j) * 136 + d];
    *reinterpret_cast<uint4*>(Vt + ((size_t)h * 128 + d) * kvLen + kv0 + 8 * kc) =
        *reinterpret_cast<const uint4*>(tmp);
  }
}

// =====================================================================
// Fused flash attention (verified round 2); epilogue extended: when addO=1
// reads f32 O, adds, writes bf16 to Ob (feeds output projection directly).
// =====================================================================
#define KSTR 136
#define FSCALE 0.08838834764831843f

__global__ __launch_bounds__(256) void flash_kernel(
    const u16* __restrict__ Q, const u16* __restrict__ K,
    const u16* __restrict__ Vt, float* __restrict__ O,
    u16* __restrict__ Ob, int kvLen, int addO) {
  __shared__ u16 Ks[64 * KSTR];
  __shared__ u16 Vs[128 * 64];
  __shared__ u16 Pb[4][16 * 72];
  __shared__ float ab[4][16];

  const int tid = threadIdx.x;
  const int lane = tid & 63;
  const int w = tid >> 6;
  const int r = lane & 15;
  const int quad = lane >> 4;
  const int h = blockIdx.y;
  const int q0 = blockIdx.x * 64;
  const int qrow = q0 + 16 * w + r;

  short8 qf[4];
  const u16* qbase = Q + (size_t)qrow * 1536 + h * 128 + 8 * quad;
#pragma unroll
  for (int ks = 0; ks < 4; ++ks)
    qf[ks] = *reinterpret_cast<const short8*>(qbase + 32 * ks);

  f32x4 Oc[8];
#pragma unroll
  for (int dt = 0; dt < 8; ++dt) Oc[dt] = (f32x4){0.f, 0.f, 0.f, 0.f};
  float m_i = -1e30f, l_i = 0.f;

  const u16* Vth = Vt + (size_t)h * 128 * kvLen;

  for (int k0 = 0; k0 < kvLen; k0 += 64) {
    __syncthreads();
#pragma unroll
    for (int i = 0; i < 4; ++i) {
      const int c = tid + 256 * i;
      const int row = c >> 4, c8 = c & 15;
      *reinterpret_cast<uint4*>(&Ks[row * KSTR + 8 * c8]) =
          *reinterpret_cast<const uint4*>(K + (size_t)(k0 + row) * 1536 + h * 128 + 8 * c8);
    }
#pragma unroll
    for (int i = 0; i < 4; ++i) {
      const int c = tid + 256 * i;
      const int d = c >> 3, kc = c & 7;
      const int kcs = kc ^ (d & 7);
      *reinterpret_cast<uint4*>(&Vs[d * 64 + 8 * kcs]) =
          *reinterpret_cast<const uint4*>(Vth + (size_t)d * kvLen + k0 + 8 * kc);
    }
    __syncthreads();

    f32x4 St[4];
#pragma unroll
    for (int mt = 0; mt < 4; ++mt) St[mt] = (f32x4){0.f, 0.f, 0.f, 0.f};
#pragma unroll
    for (int mt = 0; mt < 4; ++mt) {
      const u16* kp = &Ks[(16 * mt + r) * KSTR + 8 * quad];
#pragma unroll
      for (int ks = 0; ks < 4; ++ks) {
        const short8 af = *reinterpret_cast<const short8*>(kp + 32 * ks);
        St[mt] = __builtin_amdgcn_mfma_f32_16x16x32_bf16(af, qf[ks], St[mt], 0, 0, 0);
      }
    }

    float sv[4][4];
    float mloc = -1e30f;
#pragma unroll
    for (int mt = 0; mt < 4; ++mt)
#pragma unroll
      for (int rr = 0; rr < 4; ++rr) {
        const float x = St[mt][rr] * FSCALE;
        sv[mt][rr] = x;
        mloc = fmaxf(mloc, x);
      }
    mloc = fmaxf(mloc, __shfl_xor(mloc, 16, 64));
    mloc = fmaxf(mloc, __shfl_xor(mloc, 32, 64));
    const float mn = fmaxf(m_i, mloc);
    const float alpha = __expf(m_i - mn);
    float psum = 0.f;
    uint2 pk[4];
#pragma unroll
    for (int mt = 0; mt < 4; ++mt) {
      const float p0 = __expf(sv[mt][0] - mn);
      const float p1 = __expf(sv[mt][1] - mn);
      const float p2 = __expf(sv[mt][2] - mn);
      const float p3 = __expf(sv[mt][3] - mn);
      psum += (p0 + p1) + (p2 + p3);
      pk[mt].x = (u32)f2b(p0) | ((u32)f2b(p1) << 16);
      pk[mt].y = (u32)f2b(p2) | ((u32)f2b(p3) << 16);
    }
    psum += __shfl_xor(psum, 16, 64);
    psum += __shfl_xor(psum, 32, 64);
    l_i = l_i * alpha + psum;
    m_i = mn;

    if (quad == 0) ab[w][r] = alpha;
#pragma unroll
    for (int mt = 0; mt < 4; ++mt)
      *reinterpret_cast<uint2*>(&Pb[w][r * 72 + 16 * mt + 4 * quad]) = pk[mt];

    const float4 a4 = *reinterpret_cast<const float4*>(&ab[w][4 * quad]);
#pragma unroll
    for (int dt = 0; dt < 8; ++dt) {
      Oc[dt][0] *= a4.x; Oc[dt][1] *= a4.y; Oc[dt][2] *= a4.z; Oc[dt][3] *= a4.w;
    }

    const short8 pa0 = *reinterpret_cast<const short8*>(&Pb[w][r * 72 + 8 * quad]);
    const short8 pa1 = *reinterpret_cast<const short8*>(&Pb[w][r * 72 + 32 + 8 * quad]);

    const int sw = r & 7;
#pragma unroll
    for (int dt = 0; dt < 8; ++dt) {
      const int d = 16 * dt + r;
      const short8 b0 = *reinterpret_cast<const short8*>(&Vs[d * 64 + 8 * (quad ^ sw)]);
      const short8 b1 = *reinterpret_cast<const short8*>(&Vs[d * 64 + 8 * ((4 + quad) ^ sw)]);
      Oc[dt] = __builtin_amdgcn_mfma_f32_16x16x32_bf16(pa0, b0, Oc[dt], 0, 0, 0);
      Oc[dt] = __builtin_amdgcn_mfma_f32_16x16x32_bf16(pa1, b1, Oc[dt], 0, 0, 0);
    }
  }

  if (quad == 0) ab[w][r] = 1.0f / l_i;
  const float4 li4 = *reinterpret_cast<const float4*>(&ab[w][4 * quad]);
  const float lv[4] = {li4.x, li4.y, li4.z, li4.w};
  float* obf = O + (size_t)(q0 + 16 * w) * 1536 + h * 128;
  u16* obb = Ob + (size_t)(q0 + 16 * w) * 1536 + h * 128;
#pragma unroll
  for (int rr = 0; rr < 4; ++rr) {
    float* orow = obf + (size_t)(4 * quad + rr) * 1536 + r;
    u16* brow = obb + (size_t)(4 * quad + rr) * 1536 + r;
#pragma unroll
    for (int dt = 0; dt < 8; ++dt) {
      float v = Oc[dt][rr] * lv[rr];
      if (addO) {
        v += orow[16 * dt];
        brow[16 * dt] = f2b(v);
      } else {
        orow[16 * dt] = v;
      }
    }
  }
}

// =====================================================================
// Host orchestration
// =====================================================================
extern "C" void kernel_launch(void* const* d_in, const int* in_sizes, int n_in,
                              void* d_out, int out_size, void* d_ws, size_t ws_size,
                              hipStream_t stream) {
  (void)in_sizes; (void)n_in; (void)out_size; (void)ws_size;
  constexpr int T = 4096, TR = 1024, DIM = 1536, NH = 12;

  const float* hs  = (const float*)d_in[0];
  const float* rhs = (const float*)d_in[1];
  const float* rc  = (const float*)d_in[2];
  const float* rs  = (const float*)d_in[3];
  const float* Wq  = (const float*)d_in[4];
  const float* bq  = (const float*)d_in[5];
  const float* Wk  = (const float*)d_in[6];
  const float* bk  = (const float*)d_in[7];
  const float* Wv  = (const float*)d_in[8];
  const float* bv  = (const float*)d_in[9];
  const float* Wkr = (const float*)d_in[10];
  const float* bkr = (const float*)d_in[11];
  const float* Wvr = (const float*)d_in[12];
  const float* bvr = (const float*)d_in[13];
  const float* Wo  = (const float*)d_in[14];
  const float* bo  = (const float*)d_in[15];
  const float* gq  = (const float*)d_in[16];
  const float* gk  = (const float*)d_in[17];
  float* out = (float*)d_out;

  char* ws = (char*)d_ws;
  size_t off = 0;
  auto alloc = [&](size_t bytes) -> void* {
    void* p = ws + off;
    off += (bytes + 255) & ~(size_t)255;
    return p;
  };
  u16* bQ    = (u16*)alloc((size_t)T * DIM * 2);         // rmsnorm(q_lin) plain
  u16* bQr   = (u16*)alloc((size_t)T * DIM * 2);         // rope(rmsnorm(q_lin))
  u16* bK    = (u16*)alloc((size_t)T * DIM * 2);         // rope(rmsnorm(k_lin))
  u16* bV    = (u16*)alloc((size_t)T * DIM * 2);         // v_lin
  u16* bKr   = (u16*)alloc((size_t)TR * DIM * 2);        // ref_k (normed)
  u16* bVr   = (u16*)alloc((size_t)TR * DIM * 2);        // ref_v
  float* bO  = (float*)alloc((size_t)T * DIM * 4);       // cross-attn out (f32)
  u16* bHs   = (u16*)alloc((size_t)T * DIM * 2);         // bf16 hs; ALIAS-> VtG after QKV gemm
  u16* bRhs  = (u16*)alloc((size_t)TR * DIM * 2);        // bf16 rhs; ALIAS-> VtR after KrVr gemm
  u16* bWqkv = (u16*)alloc((size_t)3 * DIM * DIM * 2);   // WqT|WkT|WvT; ALIAS-> bOb after QKV gemm
  u16* bWr   = (u16*)alloc((size_t)2 * DIM * DIM * 2);   // WkrT|WvrT; ALIAS-> bWoT after KrVr gemm
  u16* VtG = bHs;
  u16* VtR = bRhs;
  u16* bOb = bWqkv;   // main+ref attention out, bf16 (T*DIM*2 <= 3*DIM*DIM*2)
  u16* bWoT = bWr;    // WoT (DIM*DIM*2 <= 2*DIM*DIM*2)

  const dim3 blk(256);

  // --- f32->bf16 converts ---
  conv_kernel<<<dim3(T * DIM / 8 / 256), blk, 0, stream>>>(hs, bHs, T * DIM / 8);
  conv_kernel<<<dim3(TR * DIM / 8 / 256), blk, 0, stream>>>(rhs, bRhs, TR * DIM / 8);

  // --- weight transpose-converts (W [K][N] f32 -> Wt [N][K] bf16) ---
  transconv_kernel<<<dim3(24, 24), blk, 0, stream>>>(Wq, bWqkv + 0 * (size_t)DIM * DIM, DIM, DIM);
  transconv_kernel<<<dim3(24, 24), blk, 0, stream>>>(Wk, bWqkv + 1 * (size_t)DIM * DIM, DIM, DIM);
  transconv_kernel<<<dim3(24, 24), blk, 0, stream>>>(Wv, bWqkv + 2 * (size_t)DIM * DIM, DIM, DIM);
  transconv_kernel<<<dim3(24, 24), blk, 0, stream>>>(Wkr, bWr + 0 * (size_t)DIM * DIM, DIM, DIM);
  transconv_kernel<<<dim3(24, 24), blk, 0, stream>>>(Wvr, bWr + 1 * (size_t)DIM * DIM, DIM, DIM);

  // --- fused QKV projection (segmented N: 3 x 1536), then Kr/Vr ---
  gemm128_kernel<u16><<<dim3(36, 32), blk, 0, stream>>>(
      bHs, DIM, bWqkv, DIM, bQ, bK, bV, DIM, bq, bk, bv, DIM);
  gemm128_kernel<u16><<<dim3(24, 8), blk, 0, stream>>>(
      bRhs, DIM, bWr, DIM, bKr, bVr, (u16*)nullptr, DIM, bkr, bvr, nullptr, DIM);

  // --- Wo transpose AFTER KrVr gemm (bWoT aliases bWr) ---
  transconv_kernel<<<dim3(24, 24), blk, 0, stream>>>(Wo, bWoT, DIM, DIM);

  // --- rmsnorm / rope ---
  rmsnorm_rope_kernel<<<T, blk, 0, stream>>>(bQ, gq, rc, rs, bQ, bQr);
  rmsnorm_rope_kernel<<<T, blk, 0, stream>>>(bK, gk, rc, rs, nullptr, bK);
  rmsnorm_rope_kernel<<<TR, blk, 0, stream>>>(bKr, gk, nullptr, nullptr, bKr, nullptr);

  // --- per-head V transposes (VtG aliases bHs, VtR aliases bRhs; both dead) ---
  vtrans_kernel<<<dim3(T / 64, NH), blk, 0, stream>>>(bV, VtG, T);
  vtrans_kernel<<<dim3(TR / 64, NH), blk, 0, stream>>>(bVr, VtR, TR);

  // --- flash attention: cross writes f32 bO; main adds + writes bf16 bOb ---
  flash_kernel<<<dim3(T / 64, NH), blk, 0, stream>>>(bQ, bKr, VtR, bO, bOb, TR, 0);
  flash_kernel<<<dim3(T / 64, NH), blk, 0, stream>>>(bQr, bK, VtG, bO, bOb, T, 1);

  // --- output projection (bf16 A from flash, f32 out) ---
  gemm128_kernel<float><<<dim3(12, 32), blk, 0, stream>>>(
      bOb, DIM, bWoT, DIM, out, (float*)nullptr, (float*)nullptr, DIM, bo, nullptr, nullptr, DIM);
}

// Round 4
// 568.879 us; speedup vs baseline: 3.8824x; 1.0721x over previous
//
#include <hip/hip_runtime.h>

typedef unsigned short u16;
typedef unsigned int u32;
typedef __attribute__((ext_vector_type(8))) short short8;
typedef __attribute__((ext_vector_type(4))) float f32x4;

// ---------- bf16 helpers (manual, RNE) ----------
__device__ inline u16 f2b(float f) {
  u32 u = __builtin_bit_cast(u32, f);
  u += 0x7fff + ((u >> 16) & 1);
  return (u16)(u >> 16);
}
__device__ inline float b2f(u16 u) {
  return __builtin_bit_cast(float, (u32)u << 16);
}
__device__ inline void c_store(float* p, float v) { *p = v; }
__device__ inline void c_store(u16* p, float v) { *p = f2b(v); }

__device__ inline float fexp2(float x) {
#if __has_builtin(__builtin_amdgcn_exp2f)
  return __builtin_amdgcn_exp2f(x);
#else
  return exp2f(x);
#endif
}

// ---------- async global->LDS, 16B per lane ----------
// HW contract (m104/m108): LDS dest = wave-uniform base + lane*16; g is per-lane.
typedef const __attribute__((address_space(1))) u32 gu32;
typedef __attribute__((address_space(3))) u32 lu32;
__device__ inline void async16(const u16* g, u16* l) {
  __builtin_amdgcn_global_load_lds((gu32*)g, (lu32*)l, 16, 0, 0);
}

// Q scale folded into rmsnorm producer: 1/sqrt(128) * log2(e)
#define QS (0.08838834764831843f * 1.4426950408889634f)

// =====================================================================
// 128x128x(K,BK=32) bf16 GEMM (verified round 3, unchanged).
// =====================================================================
template <typename TC>
__global__ __launch_bounds__(256) void gemm128_kernel(
    const u16* __restrict__ A, long lda,
    const u16* __restrict__ Bt, long ldb,
    TC* __restrict__ C0, TC* __restrict__ C1, TC* __restrict__ C2, long ldc,
    const float* b0, const float* b1, const float* b2,
    int K) {
  __shared__ u16 As[128 * 32];
  __shared__ u16 Bs[128 * 32];

  const int tid = threadIdx.x;
  const int lane = tid & 63;
  const int w = tid >> 6;
  const int r = lane & 15;
  const int quad = lane >> 4;
  const int m0 = blockIdx.y * 128;
  const int nb = blockIdx.x * 128;
  const int seg = nb / 1536;
  const int nc = nb - seg * 1536;
  TC* C = seg == 0 ? C0 : (seg == 1 ? C1 : C2);
  const float* bias = seg == 0 ? b0 : (seg == 1 ? b1 : b2);

  const int srow = lane >> 2;
  const int sx = ((lane & 3) ^ (srow & 3)) * 8;
  const u16* Ag = A + (size_t)(m0 + w * 32 + srow) * lda + sx;
  const u16* Bg = Bt + (size_t)(nb + w * 32 + srow) * ldb + sx;
  u16* const Al0 = &As[(w * 32) * 32];
  u16* const Al1 = &As[(w * 32 + 16) * 32];
  u16* const Bl0 = &Bs[(w * 32) * 32];
  u16* const Bl1 = &Bs[(w * 32 + 16) * 32];

  const int wm = (w >> 1) * 64;
  const int wn = (w & 1) * 64;

  f32x4 acc[4][4];
#pragma unroll
  for (int i = 0; i < 4; ++i)
#pragma unroll
    for (int j = 0; j < 4; ++j) acc[i][j] = (f32x4){0.f, 0.f, 0.f, 0.f};

  const int fco = (quad ^ (r & 3)) * 8;

  for (int kk = 0; kk < K; kk += 32) {
    __syncthreads();
    async16(Ag + kk, Al0);
    async16(Ag + kk + 16 * lda, Al1);
    async16(Bg + kk, Bl0);
    async16(Bg + kk + 16 * ldb, Bl1);
    __syncthreads();

    short8 af[4], bf[4];
#pragma unroll
    for (int mi = 0; mi < 4; ++mi)
      af[mi] = *reinterpret_cast<const short8*>(&As[(wm + 16 * mi + r) * 32 + fco]);
#pragma unroll
    for (int ni = 0; ni < 4; ++ni)
      bf[ni] = *reinterpret_cast<const short8*>(&Bs[(wn + 16 * ni + r) * 32 + fco]);
#pragma unroll
    for (int mi = 0; mi < 4; ++mi)
#pragma unroll
      for (int ni = 0; ni < 4; ++ni)
        acc[mi][ni] = __builtin_amdgcn_mfma_f32_16x16x32_bf16(af[mi], bf[ni], acc[mi][ni], 0, 0, 0);
  }

#pragma unroll
  for (int mi = 0; mi < 4; ++mi)
#pragma unroll
    for (int ni = 0; ni < 4; ++ni)
#pragma unroll
      for (int rr = 0; rr < 4; ++rr) {
        const int row = m0 + wm + 16 * mi + 4 * quad + rr;
        const int col = nc + wn + 16 * ni + r;
        c_store(&C[(size_t)row * ldc + col], acc[mi][ni][rr] + bias[col]);
      }
}

// =====================================================================
// Merged f32->bf16 convert for hs and rhs
// =====================================================================
__global__ __launch_bounds__(256) void conv2_kernel(
    const float* __restrict__ xa, u16* __restrict__ ya, int n8a,
    const float* __restrict__ xb, u16* __restrict__ yb, int n8b) {
  int i = blockIdx.x * 256 + threadIdx.x;
  const float* x;
  u16* y;
  if (i < n8a) {
    x = xa; y = ya;
  } else {
    i -= n8a;
    if (i >= n8b) return;
    x = xb; y = yb;
  }
  const float4 v0 = reinterpret_cast<const float4*>(x)[2 * i];
  const float4 v1 = reinterpret_cast<const float4*>(x)[2 * i + 1];
  uint4 rv;
  rv.x = (u32)f2b(v0.x) | ((u32)f2b(v0.y) << 16);
  rv.y = (u32)f2b(v0.z) | ((u32)f2b(v0.w) << 16);
  rv.z = (u32)f2b(v1.x) | ((u32)f2b(v1.y) << 16);
  rv.w = (u32)f2b(v1.z) | ((u32)f2b(v1.w) << 16);
  reinterpret_cast<uint4*>(y)[i] = rv;
}

// =====================================================================
// Transpose-convert body (W f32 [1536][1536] -> Wt bf16 [1536][1536]^T)
// =====================================================================
__device__ inline void transconv_body(const float* __restrict__ W, u16* __restrict__ Wt) {
  __shared__ u16 Ls[64 * 72];
  const int tid = threadIdx.x;
  const int k0 = blockIdx.y * 64;
  const int n0 = blockIdx.x * 64;
#pragma unroll
  for (int i = 0; i < 4; ++i) {
    const int c = tid + 256 * i;
    const int row = c >> 4;
    const int c4 = (c & 15) * 4;
    const float4 v = *reinterpret_cast<const float4*>(&W[(size_t)(k0 + row) * 1536 + n0 + c4]);
    Ls[(c4 + 0) * 72 + row] = f2b(v.x);
    Ls[(c4 + 1) * 72 + row] = f2b(v.y);
    Ls[(c4 + 2) * 72 + row] = f2b(v.z);
    Ls[(c4 + 3) * 72 + row] = f2b(v.w);
  }
  __syncthreads();
#pragma unroll
  for (int i = 0; i < 2; ++i) {
    const int c = tid + 256 * i;
    const int n = c >> 3;
    const int kc = (c & 7) * 8;
    u16 tmp[8];
#pragma unroll
    for (int j = 0; j < 8; ++j) tmp[j] = Ls[n * 72 + kc + j];
    *reinterpret_cast<uint4*>(&Wt[(size_t)(n0 + n) * 1536 + k0 + kc]) =
        *reinterpret_cast<const uint4*>(tmp);
  }
}

__global__ __launch_bounds__(256) void transconv5_kernel(
    const float* W0, const float* W1, const float* W2, const float* W3, const float* W4,
    u16* T0, u16* T1, u16* T2, u16* T3, u16* T4) {
  const int z = blockIdx.z;
  const float* W = z == 0 ? W0 : z == 1 ? W1 : z == 2 ? W2 : z == 3 ? W3 : W4;
  u16* Wt = z == 0 ? T0 : z == 1 ? T1 : z == 2 ? T2 : z == 3 ? T3 : T4;
  transconv_body(W, Wt);
}

__global__ __launch_bounds__(256) void transconv_kernel(
    const float* __restrict__ W, u16* __restrict__ Wt) {
  transconv_body(W, Wt);
}

// =====================================================================
// Merged RMSNorm: z=0 q-path (scaled by QS, plain+rope out), z=1 k-path
// (rope out), z=2 ref-k path (1024 rows, plain out).
// =====================================================================
__global__ __launch_bounds__(256) void rmsnorm3_kernel(
    const u16* xq, const u16* xk, const u16* xkr,
    const float* gq, const float* gk,
    const float* rc, const float* rs,
    u16* oq_plain, u16* oq_rope, u16* ok_rope, u16* okr_plain) {
  __shared__ float red[4];
  const int z = blockIdx.y;
  const int row = blockIdx.x;
  if (z == 2 && row >= 1024) return;
  const u16* x; const float* g; u16* po; u16* pr; float sc;
  if (z == 0)      { x = xq;  g = gq; po = oq_plain; pr = oq_rope; sc = QS;  }
  else if (z == 1) { x = xk;  g = gk; po = nullptr;  pr = ok_rope; sc = 1.f; }
  else             { x = xkr; g = gk; po = okr_plain; pr = nullptr; sc = 1.f; }

  const int tid = threadIdx.x;
  const u32* xr = reinterpret_cast<const u32*>(x + (size_t)row * 1536);
  float xe[3], xo[3];
  float ss = 0.f;
#pragma unroll
  for (int j = 0; j < 3; ++j) {
    const u32 u = xr[tid + 256 * j];
    const float e = b2f((u16)(u & 0xffff));
    const float o = b2f((u16)(u >> 16));
    xe[j] = e; xo[j] = o;
    ss += e * e + o * o;
  }
#pragma unroll
  for (int off = 32; off; off >>= 1) ss += __shfl_xor(ss, off, 64);
  if ((tid & 63) == 0) red[tid >> 6] = ss;
  __syncthreads();
  const float total = red[0] + red[1] + red[2] + red[3];
  const float rinv = rsqrtf(total * (1.0f / 1536.0f) + 1e-6f) * sc;
  u32* po32 = po ? reinterpret_cast<u32*>(po + (size_t)row * 1536) : nullptr;
  u32* pr32 = pr ? reinterpret_cast<u32*>(pr + (size_t)row * 1536) : nullptr;
#pragma unroll
  for (int j = 0; j < 3; ++j) {
    const int p = tid + 256 * j;
    const float2 gg = reinterpret_cast<const float2*>(g)[p];
    const float e = xe[j] * rinv * gg.x;
    const float o = xo[j] * rinv * gg.y;
    if (po32) po32[p] = (u32)f2b(e) | ((u32)f2b(o) << 16);
    if (pr32) {
      const int i = p & 63;
      const float c = rc[row * 64 + i];
      const float s = rs[row * 64 + i];
      const float re = e * c - o * s;
      const float im = e * s + o * c;
      pr32[p] = (u32)f2b(re) | ((u32)f2b(im) << 16);
    }
  }
}

// =====================================================================
// Merged per-head V transpose: z=0 main (kvLen=4096), z=1 ref (1024)
// =====================================================================
__global__ __launch_bounds__(256) void vtrans2_kernel(
    const u16* __restrict__ V0, u16* __restrict__ Vt0,
    const u16* __restrict__ V1, u16* __restrict__ Vt1) {
  __shared__ u16 Ls[64 * 136];
  const int z = blockIdx.z;
  const int kvLen = z == 0 ? 4096 : 1024;
  const int kv0 = blockIdx.x * 64;
  if (kv0 >= kvLen) return;
  const u16* V = z == 0 ? V0 : V1;
  u16* Vt = z == 0 ? Vt0 : Vt1;
  const int tid = threadIdx.x;
  const int h = blockIdx.y;
#pragma unroll
  for (int i = 0; i < 4; ++i) {
    const int c = tid + 256 * i;
    const int row = c >> 4, c8 = c & 15;
    *reinterpret_cast<uint4*>(&Ls[row * 136 + 8 * c8]) =
        *reinterpret_cast<const uint4*>(V + (size_t)(kv0 + row) * 1536 + h * 128 + 8 * c8);
  }
  __syncthreads();
#pragma unroll
  for (int i = 0; i < 4; ++i) {
    const int c = tid + 256 * i;
    const int d = c >> 3, kc = c & 7;
    u16 tmp[8];
#pragma unroll
    for (int j = 0; j < 8; ++j) tmp[j] = Ls[(8 * kc + j) * 136 + d];
    *reinterpret_cast<uint4*>(Vt + ((size_t)h * 128 + d) * kvLen + kv0 + 8 * kc) =
        *reinterpret_cast<const uint4*>(tmp);
  }
}

// =====================================================================
// Fused flash attention v2. Q pre-scaled by QS (softmax in log2 domain).
//   - K/V tiles staged via global_load_lds (async DMA, no VGPR round-trip)
//   - Ks: [64][128] unpadded, XOR-16 chunk swizzle folded into global order:
//       Ks[row][chunk p] holds K[row][p ^ (row&15)]; frag read inverts.
//   - Vs: [128][64] rows, chunk swizzle p ^ (d&7) (same LDS image as r3).
//   - rescale skipped when no row's max rises (alpha==1 exactly).
// Layout conventions identical to verified rounds 2-3.
// =====================================================================
__global__ __launch_bounds__(256) void flash_kernel(
    const u16* __restrict__ Q, const u16* __restrict__ K,
    const u16* __restrict__ Vt, float* __restrict__ O,
    u16* __restrict__ Ob, int kvLen, int addO) {
  __shared__ u16 Ks[64 * 128];
  __shared__ u16 Vs[128 * 64];
  __shared__ u16 Pb[4][16 * 72];
  __shared__ float ab[4][16];

  const int tid = threadIdx.x;
  const int lane = tid & 63;
  const int w = tid >> 6;
  const int r = lane & 15;
  const int quad = lane >> 4;
  const int h = blockIdx.y;
  const int q0 = blockIdx.x * 64;
  const int qrow = q0 + 16 * w + r;

  // Q fragments (B-operand of S^T): lane holds Q[qrow][32ks+8quad+j]
  short8 qf[4];
  const u16* qbase = Q + (size_t)qrow * 1536 + h * 128 + 8 * quad;
#pragma unroll
  for (int ks = 0; ks < 4; ++ks)
    qf[ks] = *reinterpret_cast<const short8*>(qbase + 32 * ks);

  // async staging pointers. K: wave w rows [16w,16w+16), 4 instrs x 4 rows.
  const u16* Vth = Vt + (size_t)h * 128 * kvLen;
  const u16* kg[4]; u16* kl[4];
  const u16* vg[4]; u16* vl[4];
  {
    const int p16 = lane & 15, rin = lane >> 4;   // K: 16 chunks x 4 rows
    const int p8 = lane & 7, din = lane >> 3;     // V: 8 chunks x 8 rows
#pragma unroll
    for (int j = 0; j < 4; ++j) {
      const int row = 16 * w + 4 * j + rin;
      kg[j] = K + (size_t)row * 1536 + h * 128 + 8 * (p16 ^ (row & 15));
      kl[j] = &Ks[(16 * w + 4 * j) * 128];
      const int d = 32 * w + 8 * j + din;
      vg[j] = Vth + (size_t)d * kvLen + 8 * (p8 ^ (d & 7));
      vl[j] = &Vs[(32 * w + 8 * j) * 64];
    }
  }

  f32x4 Oc[8];
#pragma unroll
  for (int dt = 0; dt < 8; ++dt) Oc[dt] = (f32x4){0.f, 0.f, 0.f, 0.f};
  float m_i = -1e30f, l_i = 0.f;

  for (int k0 = 0; k0 < kvLen; k0 += 64) {
    __syncthreads();
#pragma unroll
    for (int j = 0; j < 4; ++j) async16(kg[j] + (size_t)k0 * 1536, kl[j]);
#pragma unroll
    for (int j = 0; j < 4; ++j) async16(vg[j] + k0, vl[j]);
    __syncthreads();

    // S^T = K * Q^T (log2-domain scores; Q pre-scaled)
    f32x4 St[4];
#pragma unroll
    for (int mt = 0; mt < 4; ++mt) St[mt] = (f32x4){0.f, 0.f, 0.f, 0.f};
#pragma unroll
    for (int mt = 0; mt < 4; ++mt) {
      const u16* kp = &Ks[(16 * mt + r) * 128];
#pragma unroll
      for (int ks = 0; ks < 4; ++ks) {
        const short8 af = *reinterpret_cast<const short8*>(kp + 8 * ((quad + 4 * ks) ^ r));
        St[mt] = __builtin_amdgcn_mfma_f32_16x16x32_bf16(af, qf[ks], St[mt], 0, 0, 0);
      }
    }

    // online softmax (base 2); lane owns q-row r
    float mloc = -1e30f;
#pragma unroll
    for (int mt = 0; mt < 4; ++mt)
#pragma unroll
      for (int rr = 0; rr < 4; ++rr) mloc = fmaxf(mloc, St[mt][rr]);
    mloc = fmaxf(mloc, __shfl_xor(mloc, 16, 64));
    mloc = fmaxf(mloc, __shfl_xor(mloc, 32, 64));
    const float mn = fmaxf(m_i, mloc);

    float alpha = 1.0f;
    if (__any(mloc > m_i)) {
      alpha = fexp2(m_i - mn);
      if (quad == 0) ab[w][r] = alpha;
      const float4 a4 = *reinterpret_cast<const float4*>(&ab[w][4 * quad]);
#pragma unroll
      for (int dt = 0; dt < 8; ++dt) {
        Oc[dt][0] *= a4.x; Oc[dt][1] *= a4.y; Oc[dt][2] *= a4.z; Oc[dt][3] *= a4.w;
      }
    }

    float psum = 0.f;
    uint2 pk[4];
#pragma unroll
    for (int mt = 0; mt < 4; ++mt) {
      const float p0 = fexp2(St[mt][0] - mn);
      const float p1 = fexp2(St[mt][1] - mn);
      const float p2 = fexp2(St[mt][2] - mn);
      const float p3 = fexp2(St[mt][3] - mn);
      psum += (p0 + p1) + (p2 + p3);
      pk[mt].x = (u32)f2b(p0) | ((u32)f2b(p1) << 16);
      pk[mt].y = (u32)f2b(p2) | ((u32)f2b(p3) << 16);
    }
    psum += __shfl_xor(psum, 16, 64);
    psum += __shfl_xor(psum, 32, 64);
    l_i = l_i * alpha + psum;
    m_i = mn;

    // P -> wave-private LDS (A-operand layout [q=r][kpos])
#pragma unroll
    for (int mt = 0; mt < 4; ++mt)
      *reinterpret_cast<uint2*>(&Pb[w][r * 72 + 16 * mt + 4 * quad]) = pk[mt];

    const short8 pa0 = *reinterpret_cast<const short8*>(&Pb[w][r * 72 + 8 * quad]);
    const short8 pa1 = *reinterpret_cast<const short8*>(&Pb[w][r * 72 + 32 + 8 * quad]);

    // O += P * V
    const int sw = r & 7;
#pragma unroll
    for (int dt = 0; dt < 8; ++dt) {
      const int d = 16 * dt + r;
      const short8 b0 = *reinterpret_cast<const short8*>(&Vs[d * 64 + 8 * (quad ^ sw)]);
      const short8 b1 = *reinterpret_cast<const short8*>(&Vs[d * 64 + 8 * ((4 + quad) ^ sw)]);
      Oc[dt] = __builtin_amdgcn_mfma_f32_16x16x32_bf16(pa0, b0, Oc[dt], 0, 0, 0);
      Oc[dt] = __builtin_amdgcn_mfma_f32_16x16x32_bf16(pa1, b1, Oc[dt], 0, 0, 0);
    }
  }

  if (quad == 0) ab[w][r] = 1.0f / l_i;
  const float4 li4 = *reinterpret_cast<const float4*>(&ab[w][4 * quad]);
  const float lv[4] = {li4.x, li4.y, li4.z, li4.w};
  float* obf = O + (size_t)(q0 + 16 * w) * 1536 + h * 128;
  u16* obb = Ob + (size_t)(q0 + 16 * w) * 1536 + h * 128;
#pragma unroll
  for (int rr = 0; rr < 4; ++rr) {
    float* orow = obf + (size_t)(4 * quad + rr) * 1536 + r;
    u16* brow = obb + (size_t)(4 * quad + rr) * 1536 + r;
#pragma unroll
    for (int dt = 0; dt < 8; ++dt) {
      float v = Oc[dt][rr] * lv[rr];
      if (addO) {
        v += orow[16 * dt];
        brow[16 * dt] = f2b(v);
      } else {
        orow[16 * dt] = v;
      }
    }
  }
}

// =====================================================================
// Host orchestration (10 dispatches)
// =====================================================================
extern "C" void kernel_launch(void* const* d_in, const int* in_sizes, int n_in,
                              void* d_out, int out_size, void* d_ws, size_t ws_size,
                              hipStream_t stream) {
  (void)in_sizes; (void)n_in; (void)out_size; (void)ws_size;
  constexpr int T = 4096, TR = 1024, DIM = 1536, NH = 12;

  const float* hs  = (const float*)d_in[0];
  const float* rhs = (const float*)d_in[1];
  const float* rc  = (const float*)d_in[2];
  const float* rs  = (const float*)d_in[3];
  const float* Wq  = (const float*)d_in[4];
  const float* bq  = (const float*)d_in[5];
  const float* Wk  = (const float*)d_in[6];
  const float* bk  = (const float*)d_in[7];
  const float* Wv  = (const float*)d_in[8];
  const float* bv  = (const float*)d_in[9];
  const float* Wkr = (const float*)d_in[10];
  const float* bkr = (const float*)d_in[11];
  const float* Wvr = (const float*)d_in[12];
  const float* bvr = (const float*)d_in[13];
  const float* Wo  = (const float*)d_in[14];
  const float* bo  = (const float*)d_in[15];
  const float* gq  = (const float*)d_in[16];
  const float* gk  = (const float*)d_in[17];
  float* out = (float*)d_out;

  char* ws = (char*)d_ws;
  size_t off = 0;
  auto alloc = [&](size_t bytes) -> void* {
    void* p = ws + off;
    off += (bytes + 255) & ~(size_t)255;
    return p;
  };
  u16* bQ    = (u16*)alloc((size_t)T * DIM * 2);
  u16* bQr   = (u16*)alloc((size_t)T * DIM * 2);
  u16* bK    = (u16*)alloc((size_t)T * DIM * 2);
  u16* bV    = (u16*)alloc((size_t)T * DIM * 2);
  u16* bKr   = (u16*)alloc((size_t)TR * DIM * 2);
  u16* bVr   = (u16*)alloc((size_t)TR * DIM * 2);
  float* bO  = (float*)alloc((size_t)T * DIM * 4);
  u16* bHs   = (u16*)alloc((size_t)T * DIM * 2);       // bf16 hs; ALIAS-> VtG
  u16* bRhs  = (u16*)alloc((size_t)TR * DIM * 2);      // bf16 rhs; ALIAS-> VtR
  u16* bWqkv = (u16*)alloc((size_t)3 * DIM * DIM * 2); // WqT|WkT|WvT; ALIAS-> bOb
  u16* bWr   = (u16*)alloc((size_t)2 * DIM * DIM * 2); // WkrT|WvrT; ALIAS-> bWoT
  u16* VtG = bHs;
  u16* VtR = bRhs;
  u16* bOb = bWqkv;
  u16* bWoT = bWr;

  const dim3 blk(256);

  // 1. f32->bf16 converts (merged)
  conv2_kernel<<<dim3((T * DIM / 8 + TR * DIM / 8 + 255) / 256), blk, 0, stream>>>(
      hs, bHs, T * DIM / 8, rhs, bRhs, TR * DIM / 8);

  // 2. weight transpose-converts (Wq,Wk,Wv,Wkr,Wvr merged)
  transconv5_kernel<<<dim3(24, 24, 5), blk, 0, stream>>>(
      Wq, Wk, Wv, Wkr, Wvr,
      bWqkv + 0 * (size_t)DIM * DIM, bWqkv + 1 * (size_t)DIM * DIM,
      bWqkv + 2 * (size_t)DIM * DIM, bWr + 0 * (size_t)DIM * DIM,
      bWr + 1 * (size_t)DIM * DIM);

  // 3-4. projections
  gemm128_kernel<u16><<<dim3(36, 32), blk, 0, stream>>>(
      bHs, DIM, bWqkv, DIM, bQ, bK, bV, DIM, bq, bk, bv, DIM);
  gemm128_kernel<u16><<<dim3(24, 8), blk, 0, stream>>>(
      bRhs, DIM, bWr, DIM, bKr, bVr, (u16*)nullptr, DIM, bkr, bvr, nullptr, DIM);

  // 5. Wo transpose AFTER KrVr gemm (bWoT aliases bWr)
  transconv_kernel<<<dim3(24, 24), blk, 0, stream>>>(Wo, bWoT);

  // 6. rmsnorm/rope (merged; q-path pre-scaled by QS)
  rmsnorm3_kernel<<<dim3(T, 3), blk, 0, stream>>>(
      bQ, bK, bKr, gq, gk, rc, rs, bQ, bQr, bK, bKr);

  // 7. per-head V transposes (merged; aliases are dead buffers)
  vtrans2_kernel<<<dim3(T / 64, NH, 2), blk, 0, stream>>>(bV, VtG, bVr, VtR);

  // 8-9. flash attention: cross writes f32 bO; main adds + writes bf16 bOb
  flash_kernel<<<dim3(T / 64, NH), blk, 0, stream>>>(bQ, bKr, VtR, bO, bOb, TR, 0);
  flash_kernel<<<dim3(T / 64, NH), blk, 0, stream>>>(bQr, bK, VtG, bO, bOb, T, 1);

  // 10. output projection
  gemm128_kernel<float><<<dim3(12, 32), blk, 0, stream>>>(
      bOb, DIM, bWoT, DIM, out, (float*)nullptr, (float*)nullptr, DIM, bo, nullptr, nullptr, DIM);
}